// Round 15
// baseline (47.077 us; speedup 1.0000x reference)
//
#include <hip/hip_runtime.h>

#define IND 256
#define KC  32

__global__ __launch_bounds__(256, 4)
void FeatureEncodingLayer_30374008718005_kernel(
        const float* __restrict__ X,      // [1024][256]
        const float* __restrict__ W,      // [4096][256]
        const float* __restrict__ bias,   // [4096]
        float* __restrict__ outf)         // [1024][4][4][2048] float32 = Re(kron)
{
    // Double-buffered W tile, k-major, XOR-swizzled: col = u ^ ((k>>2)<<2).
    // X never touches LDS (wave-uniform scalar loads).
    __shared__ float Ws[2][KC][128];

    const int tid  = threadIdx.x;
    const int lane = tid & 63;
    const int wid  = __builtin_amdgcn_readfirstlane(tid >> 6);  // wave 0..3

    const int ut = blockIdx.x & 31;    // 32 unit tiles x 128 units
    const int bt = blockIdx.x >> 5;    // 32 batch tiles x 32 batches
    const int b0 = bt * 32;
    const int u0 = ut * 128;
    const int p0 = ut * 64;

    // staging roles: 128 u x 32 k per chunk
    const int q  = tid & 7;    // k-quad (k = 4q..4q+3)
    const int rq = tid >> 3;   // row subgroup 0..31

    const float* xw = X + (size_t)(b0 + 8 * wid) * IND;   // wave-uniform

    float acc[8][2];
#pragma unroll
    for (int i = 0; i < 8; ++i) { acc[i][0] = 0.f; acc[i][1] = 0.f; }

    float4 pf[4];
#define STAGE_LOAD(c) do {                                                     \
    _Pragma("unroll")                                                          \
    for (int j = 0; j < 4; ++j)                                                \
        pf[j] = *reinterpret_cast<const float4*>(                              \
            W + (size_t)(u0 + rq + 32 * j) * IND + (c) * KC + q * 4);          \
    } while (0)

#define STAGE_WRITE(buf) do {                                                  \
    _Pragma("unroll")                                                          \
    for (int j = 0; j < 4; ++j) {                                              \
        const int col = (rq + 32 * j) ^ (q << 2);                              \
        Ws[buf][q * 4 + 0][col] = pf[j].x;                                     \
        Ws[buf][q * 4 + 1][col] = pf[j].y;                                     \
        Ws[buf][q * 4 + 2][col] = pf[j].z;                                     \
        Ws[buf][q * 4 + 3][col] = pf[j].w;                                     \
    }                                                                          \
    } while (0)

    STAGE_LOAD(0);
    STAGE_WRITE(0);
    __syncthreads();

    for (int c = 0; c < IND / KC; ++c) {
        const int cur = c & 1;
        if (c < IND / KC - 1) STAGE_LOAD(c + 1);   // prefetch (no wait yet)

        // ---- zero-slot stores for this chunk: issued AFTER the prefetch loads
        // (so STAGE_WRITE's vmcnt wait never drains them), hidden under compute.
        // zrc table {1,2,4,7,8,11,13,14} bit-packed (no runtime-indexed array).
        {
            const int zrc = (int)((0xEDB87421u >> (4 * c)) & 0xFu);
            float* zp = outf + (size_t)(b0 + 8 * wid) * 32768
                       + (size_t)zrc * 2048 + p0 + lane;
#pragma unroll
            for (int i = 0; i < 8; ++i)
                zp[(size_t)i * 32768] = 0.f;     // coalesced 256B per wave-store
        }

        const float* xc = xw + c * KC;             // wave-uniform -> scalar loads
#pragma unroll 4
        for (int k = 0; k < KC; ++k) {
            const int s = ((k >> 2) & 7) << 2;
            const float2 wv = *reinterpret_cast<const float2*>(
                &Ws[cur][k][(2 * lane) ^ s]);      // ds_read_b64, conflict-free
#pragma unroll
            for (int i = 0; i < 8; ++i) {
                const float xv = xc[i * IND + k];
                acc[i][0] = fmaf(xv, wv.x, acc[i][0]);
                acc[i][1] = fmaf(xv, wv.y, acc[i][1]);
            }
        }
        if (c < IND / KC - 1) {
            STAGE_WRITE(cur ^ 1);                  // waits only its own loads
            __syncthreads();                       // one barrier per chunk
        }
    }
#undef STAGE_LOAD
#undef STAGE_WRITE

    // ---- epilogue: lane owns pair p0+lane; store ONLY the 8 nonzero slots ----
    const float2 bv = *reinterpret_cast<const float2*>(bias + u0 + 2 * lane);

#pragma unroll
    for (int i = 0; i < 8; ++i) {
        const int b = b0 + 8 * wid + i;
        const float tA = acc[i][0] + bv.x;
        const float tB = acc[i][1] + bv.y;
        float sA, cA, sB, cB;
        __sincosf(tA, &sA, &cA);
        __sincosf(tB, &sB, &cB);
        const float ca = 0.5f * (1.f + cA);   // cos^2(tA/2)
        const float sa = 0.5f * (1.f - cA);   // sin^2(tA/2)
        const float cb = 0.5f * (1.f + cB);
        const float sb = 0.5f * (1.f - cB);
        const float oo = 0.25f * sA * sB;     // sin(tA)/2 * sin(tB)/2

        float* bp = outf + (size_t)b * 32768 + p0 + lane;
        bp[ 0 * 2048] =  ca * cb;
        bp[ 3 * 2048] = -oo;
        bp[ 5 * 2048] =  ca * sb;
        bp[ 6 * 2048] =  oo;
        bp[ 9 * 2048] =  oo;
        bp[10 * 2048] =  sa * cb;
        bp[12 * 2048] = -oo;
        bp[15 * 2048] =  sa * sb;
    }
}

extern "C" void kernel_launch(void* const* d_in, const int* in_sizes, int n_in,
                              void* d_out, int out_size, void* d_ws, size_t ws_size,
                              hipStream_t stream) {
    const float* X  = (const float*)d_in[0];
    const float* W  = (const float*)d_in[1];
    const float* bv = (const float*)d_in[2];

    // 32 batch-tiles x 32 unit-tiles = 1024 blocks, 256 threads, ~4 blocks/CU
    FeatureEncodingLayer_30374008718005_kernel<<<dim3(1024), dim3(256), 0, stream>>>(
        X, W, bv, (float*)d_out);
}